// Round 4
// baseline (884.678 us; speedup 1.0000x reference)
//
#include <hip/hip_runtime.h>

// Problem: out[b,s,o] = sum_i x[b,s,i] * (deq W)[o,i]
//   x: (8,512,4096) fp32  -> A [M=4096][K=4096]
//   packed_weight: (11008, 2048) int32, each holds one byte = 2 nibbles (hi first)
//   scale/zero_point: (11008, 32) fp32, group size 128 along K
//   out: (8,512,11008) fp32 -> C [M=4096][N=11008]
//
// Strategy: pre-dequant W -> bf16 [N][K] in ws, pre-convert x -> bf16 [M][K] in ws,
// then m97-style 128x128 bf16 MFMA GEMM (B^T layout), fp32 accum.
// WS NEED: 33,554,432 (A) + 90,177,536 (W) = 123,731,968 bytes.

typedef unsigned short u16;
typedef __bf16  bf16x8 __attribute__((ext_vector_type(8)));
typedef float   f32x4  __attribute__((ext_vector_type(4)));

#define K_DIM 4096
#define N_DIM 11008
#define M_DIM 4096
#define TM 128
#define TN 128
#define TK 32

__device__ __forceinline__ u16 f2bf(float f) {
    unsigned u = __float_as_uint(f);
    return (u16)((u + 0x7fffu + ((u >> 16) & 1u)) >> 16);  // RNE
}

__device__ __forceinline__ void gload_lds16(const void* g, void* l) {
    __builtin_amdgcn_global_load_lds(
        (const __attribute__((address_space(1))) void*)g,
        (__attribute__((address_space(3))) void*)l, 16, 0, 0);
}

// ---- x fp32 -> bf16 ----  16,777,216 elems, 8/thread, 8192 blocks x 256
__global__ void convert_x_kernel(const float* __restrict__ x, u16* __restrict__ a) {
    size_t i = ((size_t)blockIdx.x * 256 + threadIdx.x) * 8;
    float4 v0 = *(const float4*)&x[i];
    float4 v1 = *(const float4*)&x[i + 4];
    uint4 o;
    o.x = (unsigned)f2bf(v0.x) | ((unsigned)f2bf(v0.y) << 16);
    o.y = (unsigned)f2bf(v0.z) | ((unsigned)f2bf(v0.w) << 16);
    o.z = (unsigned)f2bf(v1.x) | ((unsigned)f2bf(v1.y) << 16);
    o.w = (unsigned)f2bf(v1.z) | ((unsigned)f2bf(v1.w) << 16);
    *(uint4*)&a[i] = o;
}

// ---- dequant packed int4 -> bf16 W[N][K] ----
// chunk c: o = c>>9, j4 = c&511 (4 packed int32 -> 8 bf16). 22016 blocks x 256.
__global__ void dequant_w_kernel(const int* __restrict__ pw,
                                 const float* __restrict__ sc,
                                 const float* __restrict__ zp,
                                 u16* __restrict__ w) {
    int c = blockIdx.x * 256 + threadIdx.x;          // [0, 5,636,096)
    int o = c >> 9;
    int j4 = c & 511;
    int g = j4 >> 4;                                  // group = (j4*8)/128 = j4/16
    float s = sc[(o << 5) + g];
    float z = zp[(o << 5) + g];
    int4 p = *(const int4*)&pw[((size_t)o << 11) + (j4 << 2)];
    int v[4] = {p.x, p.y, p.z, p.w};
    unsigned r[4];
#pragma unroll
    for (int b = 0; b < 4; ++b) {
        u16 hi = f2bf(fmaf((float)((v[b] >> 4) & 15), s, z));
        u16 lo = f2bf(fmaf((float)(v[b] & 15), s, z));
        r[b] = (unsigned)hi | ((unsigned)lo << 16);   // hi nibble first -> even index
    }
    uint4 ov = {r[0], r[1], r[2], r[3]};
    *(uint4*)&w[(size_t)c * 8] = ov;
}

// ---- bf16 GEMM, B^T layout (both A and B are K-major) ----
// 128x128 tile, BK=32, 256 thr = 4 waves (2x2), each wave 64x64 = 4x4 frags 16x16x32.
__global__ __launch_bounds__(256) void gemm_bt_kernel(
    const u16* __restrict__ A,   // [M][K] bf16
    const u16* __restrict__ B,   // [N][K] bf16
    float* __restrict__ C)       // [M][N]
{
    __shared__ __align__(16) u16 As[TM * TK];  // 8KB, linear (global_load_lds constraint)
    __shared__ __align__(16) u16 Bs[TN * TK];  // 8KB

    const int t = threadIdx.x;
    const int wave = t >> 6;
    const int lane = t & 63;

    // XCD-aware bijective swizzle: 2752 blocks, 2752 % 8 == 0, chunk = 344
    const int nbn = N_DIM / TN;              // 86
    const int chunk = (gridDim.x) >> 3;      // 344
    int swz = (blockIdx.x & 7) * chunk + (blockIdx.x >> 3);
    const int m0 = (swz / nbn) * TM;
    const int n0 = (swz % nbn) * TN;

    const int lwm = (wave >> 1) * 64;
    const int lwn = (wave & 1) * 64;
    const int r16 = lane & 15;
    const int kq  = lane >> 4;               // 0..3

    // staging: chunk chk = wave*2 + c covers rows [chk*16, chk*16+16), 1KB each
    const int srow = lane >> 2;              // row within chunk
    const int scol = (lane & 3) * 8;         // K-element offset of this lane's 16B

    const u16* Abase = A + (size_t)m0 * K_DIM;
    const u16* Bbase = B + (size_t)n0 * K_DIM;

    f32x4 acc[4][4] = {};

    for (int k0 = 0; k0 < K_DIM; k0 += TK) {
#pragma unroll
        for (int c = 0; c < 2; ++c) {
            const int chk = wave * 2 + c;
            const int row = chk * 16 + srow;
            gload_lds16(Abase + (size_t)row * K_DIM + k0 + scol, &As[chk * 512]);
            gload_lds16(Bbase + (size_t)row * K_DIM + k0 + scol, &Bs[chk * 512]);
        }
        __syncthreads();   // drains vmcnt -> staged tiles visible

        bf16x8 af[4], bf[4];
#pragma unroll
        for (int f = 0; f < 4; ++f)
            af[f] = *(const bf16x8*)&As[(lwm + f * 16 + r16) * TK + kq * 8];
#pragma unroll
        for (int f = 0; f < 4; ++f)
            bf[f] = *(const bf16x8*)&Bs[(lwn + f * 16 + r16) * TK + kq * 8];

#pragma unroll
        for (int i = 0; i < 4; ++i)
#pragma unroll
            for (int j = 0; j < 4; ++j)
                acc[i][j] = __builtin_amdgcn_mfma_f32_16x16x32_bf16(
                    af[i], bf[j], acc[i][j], 0, 0, 0);

        __syncthreads();   // all waves done reading before next stage overwrites
    }

    // epilogue: D mapping col = lane&15, row = (lane>>4)*4 + reg
#pragma unroll
    for (int i = 0; i < 4; ++i) {
        const int row = m0 + lwm + i * 16 + kq * 4;
#pragma unroll
        for (int j = 0; j < 4; ++j) {
            const int col = n0 + lwn + j * 16 + r16;
            float* cp = &C[(size_t)row * N_DIM + col];
#pragma unroll
            for (int r = 0; r < 4; ++r)
                cp[(size_t)r * N_DIM] = acc[i][j][r];
        }
    }
}

extern "C" void kernel_launch(void* const* d_in, const int* in_sizes, int n_in,
                              void* d_out, int out_size, void* d_ws, size_t ws_size,
                              hipStream_t stream) {
    const float* x  = (const float*)d_in[0];
    const int*   pw = (const int*)d_in[1];
    const float* sc = (const float*)d_in[2];
    const float* zp = (const float*)d_in[3];
    float* out = (float*)d_out;

    u16* Abf = (u16*)d_ws;                                   // 33,554,432 B
    u16* Wbf = (u16*)((char*)d_ws + (size_t)33554432);       // 90,177,536 B

    convert_x_kernel<<<8192, 256, 0, stream>>>(x, Abf);
    dequant_w_kernel<<<22016, 256, 0, stream>>>(pw, sc, zp, Wbf);

    const int grid = (M_DIM / TM) * (N_DIM / TN);            // 32 * 86 = 2752
    gemm_bt_kernel<<<grid, 256, 0, stream>>>(Abf, Wbf, out);
}

// Round 11
// 657.766 us; speedup vs baseline: 1.3450x; 1.3450x over previous
//
#include <hip/hip_runtime.h>

// out[b,s,o] = sum_i x[b,s,i] * deq(W)[o,i]
// A = x as [M=4096][K=4096] bf16 (pre-converted), B = deq W as [N=11008][K] bf16.
// GEMM: 256x256 tile, BK=32, ring-4 LDS (128KB), counted-vmcnt pipeline (lead 2),
// 2 phases/K-tile with barrier+lgkmcnt+setprio structure, XCD swizzle, T2 16B-XOR swizzle.

typedef unsigned short u16;
typedef __bf16  bf16x8 __attribute__((ext_vector_type(8)));
typedef float   f32x4  __attribute__((ext_vector_type(4)));

#define K_DIM 4096
#define N_DIM 11008
#define M_DIM 4096
#define BM 256
#define BN 256
#define BK 32
#define NT (K_DIM / BK)     // 128
#define SLOT 16384          // u16 per ring slot: A 8192 + B 8192 (32KB)
#define NSLOT 4             // 128KB total LDS

__device__ __forceinline__ u16 f2bf(float f) {
    unsigned u = __float_as_uint(f);
    return (u16)((u + 0x7fffu + ((u >> 16) & 1u)) >> 16);  // RNE
}

__device__ __forceinline__ void gload_lds16(const void* g, void* l) {
    __builtin_amdgcn_global_load_lds(
        (const __attribute__((address_space(1))) void*)g,
        (__attribute__((address_space(3))) void*)l, 16, 0, 0);
}

// ---- x fp32 -> bf16 ----
__global__ void convert_x_kernel(const float* __restrict__ x, u16* __restrict__ a) {
    size_t i = ((size_t)blockIdx.x * 256 + threadIdx.x) * 8;
    float4 v0 = *(const float4*)&x[i];
    float4 v1 = *(const float4*)&x[i + 4];
    uint4 o;
    o.x = (unsigned)f2bf(v0.x) | ((unsigned)f2bf(v0.y) << 16);
    o.y = (unsigned)f2bf(v0.z) | ((unsigned)f2bf(v0.w) << 16);
    o.z = (unsigned)f2bf(v1.x) | ((unsigned)f2bf(v1.y) << 16);
    o.w = (unsigned)f2bf(v1.z) | ((unsigned)f2bf(v1.w) << 16);
    *(uint4*)&a[i] = o;
}

// ---- dequant packed int4 -> bf16 W[N][K] ----
__global__ void dequant_w_kernel(const int* __restrict__ pw,
                                 const float* __restrict__ sc,
                                 const float* __restrict__ zp,
                                 u16* __restrict__ w) {
    int c = blockIdx.x * 256 + threadIdx.x;
    int o = c >> 9;
    int j4 = c & 511;
    int g = j4 >> 4;
    float s = sc[(o << 5) + g];
    float z = zp[(o << 5) + g];
    int4 p = *(const int4*)&pw[((size_t)o << 11) + (j4 << 2)];
    int v[4] = {p.x, p.y, p.z, p.w};
    unsigned r[4];
#pragma unroll
    for (int b = 0; b < 4; ++b) {
        u16 hi = f2bf(fmaf((float)((v[b] >> 4) & 15), s, z));
        u16 lo = f2bf(fmaf((float)(v[b] & 15), s, z));
        r[b] = (unsigned)hi | ((unsigned)lo << 16);
    }
    uint4 ov = {r[0], r[1], r[2], r[3]};
    *(uint4*)&w[(size_t)c * 8] = ov;
}

// ---- deep-pipelined bf16 GEMM (B^T layout) ----
// 8 waves (2M x 4N), per-wave 128x64 output = acc[8][4] of 16x16 frags.
// Ring-4 K-tile slots; iteration t stages K-tile t+2; vmcnt(4) gates t+1.
__global__ __launch_bounds__(512, 2) void gemm_bt_kernel(
    const u16* __restrict__ A,   // [M][K]
    const u16* __restrict__ B,   // [N][K]
    float* __restrict__ C)       // [M][N]
{
    __shared__ __align__(16) u16 lds[NSLOT * SLOT];  // 131072 B

    const int t    = threadIdx.x;
    const int wave = t >> 6;
    const int lane = t & 63;

    // XCD-aware bijective swizzle: 688 blocks, 688 % 8 == 0, chunk 86
    const int nbn = N_DIM / BN;               // 43
    int swz = (blockIdx.x & 7) * (gridDim.x >> 3) + (blockIdx.x >> 3);
    const int m0 = (swz / nbn) * BM;
    const int n0 = (swz % nbn) * BN;

    const int wm  = wave >> 2;                // 0..1  (M half)
    const int wn  = wave & 3;                 // 0..3  (N quarter)
    const int r16 = lane & 15;
    const int kq  = lane >> 4;                // 0..3

    // ---- ds_read offsets (u16 within slot), T2 swizzle: idx ^= ((row&3)<<3) ----
    int aoff[8], boff[4];
#pragma unroll
    for (int f = 0; f < 8; ++f) {
        int row = wm * 128 + f * 16 + r16;
        aoff[f] = (row * 32 + kq * 8) ^ ((r16 & 3) << 3);
    }
#pragma unroll
    for (int j = 0; j < 4; ++j) {
        int row = wn * 64 + j * 16 + r16;
        boff[j] = 8192 + ((row * 32 + kq * 8) ^ ((r16 & 3) << 3));
    }

    // ---- staging: thread tau covers dest 16B chunk tau (+ i*512) of a 16KB half ----
    // dest row = i*128 + (tau>>2), dest 16B slot = tau&3; source slot pre-swizzled
    // so that LDS[j] = G[pi(j)] with pi = XOR((row&3)<<4) at byte level (rule 21).
    const int srow = t >> 2;                          // 0..127
    const int sswz = (t & 3) ^ (srow & 3);            // swizzled source 16B slot
    const u16* pA = A + (size_t)(m0 + srow) * K_DIM + sswz * 8;
    const u16* pB = B + (size_t)(n0 + srow) * K_DIM + sswz * 8;
    const int dstW = wave * 512;                      // u16; hw adds lane*16B

    auto stageA = [&](int s, int tt) {
#pragma unroll
        for (int i = 0; i < 2; ++i)
            gload_lds16(pA + (size_t)i * 128 * K_DIM + tt * BK,
                        &lds[s * SLOT + i * 4096 + dstW]);
    };
    auto stageB = [&](int s, int tt) {
#pragma unroll
        for (int i = 0; i < 2; ++i)
            gload_lds16(pB + (size_t)i * 128 * K_DIM + tt * BK,
                        &lds[s * SLOT + 8192 + i * 4096 + dstW]);
    };

    f32x4 acc[8][4] = {};

    // ---- prologue: stage K0, K1; force K0 landed (vmcnt(4) leaves K1 in flight) ----
    stageA(0, 0); stageB(0, 0);
    stageA(1, 1); stageB(1, 1);
    asm volatile("s_waitcnt vmcnt(4)" ::: "memory");
    __builtin_amdgcn_s_barrier();

    for (int kt = 0; kt < NT; ++kt) {
        const int s  = kt & 3;
        const int sw = (kt + 2) & 3;
        const bool doStage = (kt + 2) < NT;

        bf16x8 bfr[4], afr[4];

        // ======== phase 0: B all + A frags 0..3 ========
#pragma unroll
        for (int j = 0; j < 4; ++j)
            bfr[j] = *(const bf16x8*)&lds[s * SLOT + boff[j]];
#pragma unroll
        for (int f = 0; f < 4; ++f)
            afr[f] = *(const bf16x8*)&lds[s * SLOT + aoff[f]];
        if (doStage) stageA(sw, kt + 2);
        __builtin_amdgcn_s_barrier();
        asm volatile("s_waitcnt lgkmcnt(0)" ::: "memory");
        __builtin_amdgcn_sched_barrier(0);
        __builtin_amdgcn_s_setprio(1);
#pragma unroll
        for (int f = 0; f < 4; ++f)
#pragma unroll
            for (int j = 0; j < 4; ++j)
                acc[f][j] = __builtin_amdgcn_mfma_f32_16x16x32_bf16(
                    afr[f], bfr[j], acc[f][j], 0, 0, 0);
        __builtin_amdgcn_s_setprio(0);
        __builtin_amdgcn_s_barrier();

        // ======== phase 1: A frags 4..7 (B kept in regs) ========
#pragma unroll
        for (int f = 0; f < 4; ++f)
            afr[f] = *(const bf16x8*)&lds[s * SLOT + aoff[4 + f]];
        if (doStage) stageB(sw, kt + 2);
        __builtin_amdgcn_s_barrier();
        asm volatile("s_waitcnt lgkmcnt(0)" ::: "memory");
        __builtin_amdgcn_sched_barrier(0);
        __builtin_amdgcn_s_setprio(1);
#pragma unroll
        for (int f = 0; f < 4; ++f)
#pragma unroll
            for (int j = 0; j < 4; ++j)
                acc[4 + f][j] = __builtin_amdgcn_mfma_f32_16x16x32_bf16(
                    afr[f], bfr[j], acc[4 + f][j], 0, 0, 0);
        __builtin_amdgcn_s_setprio(0);
        // gate next K-tile: everything except t+2's 4 loads must have landed
        if (doStage) asm volatile("s_waitcnt vmcnt(4)" ::: "memory");
        else         asm volatile("s_waitcnt vmcnt(0)" ::: "memory");
        __builtin_amdgcn_s_barrier();
    }

    // ---- epilogue: D mapping col = lane&15, row = (lane>>4)*4 + reg ----
#pragma unroll
    for (int f = 0; f < 8; ++f) {
        const int row = m0 + wm * 128 + f * 16 + kq * 4;
#pragma unroll
        for (int j = 0; j < 4; ++j) {
            const int col = n0 + wn * 64 + j * 16 + r16;
            float* cp = &C[(size_t)row * N_DIM + col];
#pragma unroll
            for (int r = 0; r < 4; ++r)
                cp[(size_t)r * N_DIM] = acc[f][j][r];
        }
    }
}

extern "C" void kernel_launch(void* const* d_in, const int* in_sizes, int n_in,
                              void* d_out, int out_size, void* d_ws, size_t ws_size,
                              hipStream_t stream) {
    const float* x  = (const float*)d_in[0];
    const int*   pw = (const int*)d_in[1];
    const float* sc = (const float*)d_in[2];
    const float* zp = (const float*)d_in[3];
    float* out = (float*)d_out;

    u16* Abf = (u16*)d_ws;                                   // 33,554,432 B
    u16* Wbf = (u16*)((char*)d_ws + (size_t)33554432);       // 90,177,536 B

    convert_x_kernel<<<8192, 256, 0, stream>>>(x, Abf);
    dequant_w_kernel<<<22016, 256, 0, stream>>>(pw, sc, zp, Wbf);

    const int grid = (M_DIM / BM) * (N_DIM / BN);            // 16 * 43 = 688
    gemm_bt_kernel<<<grid, 512, 0, stream>>>(Abf, Wbf, out);
}

// Round 14
// 648.256 us; speedup vs baseline: 1.3647x; 1.0147x over previous
//
#include <hip/hip_runtime.h>

// out[b,s,o] = sum_i x[b,s,i] * deq(W)[o,i]
// A = x as [M=4096][K=4096] bf16 (pre-converted), B = deq W as [N=11008][K] bf16.
// GEMM: 256x256 tile, BK=32, ring-4 LDS (128KB), counted-vmcnt pipeline (lead 2).
// R12 change: 8-way slot swizzle slot' = kq ^ ((row>>1)&3)  (was ^(row&3), only 4-way).
//   granule mod 8 = ((row&1)<<2)|(kq^((row>>1)&3)) -> 8 distinct across 8 rows -> 2-way free.

typedef unsigned short u16;
typedef __bf16  bf16x8 __attribute__((ext_vector_type(8)));
typedef float   f32x4  __attribute__((ext_vector_type(4)));

#define K_DIM 4096
#define N_DIM 11008
#define M_DIM 4096
#define BM 256
#define BN 256
#define BK 32
#define NT (K_DIM / BK)     // 128
#define SLOT 16384          // u16 per ring slot: A 8192 + B 8192 (32KB)
#define NSLOT 4             // 128KB total LDS

__device__ __forceinline__ u16 f2bf(float f) {
    unsigned u = __float_as_uint(f);
    return (u16)((u + 0x7fffu + ((u >> 16) & 1u)) >> 16);  // RNE
}

__device__ __forceinline__ void gload_lds16(const void* g, void* l) {
    __builtin_amdgcn_global_load_lds(
        (const __attribute__((address_space(1))) void*)g,
        (__attribute__((address_space(3))) void*)l, 16, 0, 0);
}

// ---- x fp32 -> bf16 ----
__global__ void convert_x_kernel(const float* __restrict__ x, u16* __restrict__ a) {
    size_t i = ((size_t)blockIdx.x * 256 + threadIdx.x) * 8;
    float4 v0 = *(const float4*)&x[i];
    float4 v1 = *(const float4*)&x[i + 4];
    uint4 o;
    o.x = (unsigned)f2bf(v0.x) | ((unsigned)f2bf(v0.y) << 16);
    o.y = (unsigned)f2bf(v0.z) | ((unsigned)f2bf(v0.w) << 16);
    o.z = (unsigned)f2bf(v1.x) | ((unsigned)f2bf(v1.y) << 16);
    o.w = (unsigned)f2bf(v1.z) | ((unsigned)f2bf(v1.w) << 16);
    *(uint4*)&a[i] = o;
}

// ---- dequant packed int4 -> bf16 W[N][K] ----
__global__ void dequant_w_kernel(const int* __restrict__ pw,
                                 const float* __restrict__ sc,
                                 const float* __restrict__ zp,
                                 u16* __restrict__ w) {
    int c = blockIdx.x * 256 + threadIdx.x;
    int o = c >> 9;
    int j4 = c & 511;
    int g = j4 >> 4;
    float s = sc[(o << 5) + g];
    float z = zp[(o << 5) + g];
    int4 p = *(const int4*)&pw[((size_t)o << 11) + (j4 << 2)];
    int v[4] = {p.x, p.y, p.z, p.w};
    unsigned r[4];
#pragma unroll
    for (int b = 0; b < 4; ++b) {
        u16 hi = f2bf(fmaf((float)((v[b] >> 4) & 15), s, z));
        u16 lo = f2bf(fmaf((float)(v[b] & 15), s, z));
        r[b] = (unsigned)hi | ((unsigned)lo << 16);
    }
    uint4 ov = {r[0], r[1], r[2], r[3]};
    *(uint4*)&w[(size_t)c * 8] = ov;
}

// ---- deep-pipelined bf16 GEMM (B^T layout) ----
// 8 waves (2M x 4N), per-wave 128x64 output = acc[8][4] of 16x16 frags.
// Ring-4 K-tile slots; iteration t stages K-tile t+2; vmcnt(4) gates t+1.
__global__ __launch_bounds__(512, 2) void gemm_bt_kernel(
    const u16* __restrict__ A,   // [M][K]
    const u16* __restrict__ B,   // [N][K]
    float* __restrict__ C)       // [M][N]
{
    __shared__ __align__(16) u16 lds[NSLOT * SLOT];  // 131072 B

    const int t    = threadIdx.x;
    const int wave = t >> 6;
    const int lane = t & 63;

    // XCD-aware bijective swizzle: 688 blocks, 688 % 8 == 0, chunk 86
    const int nbn = N_DIM / BN;               // 43
    int swz = (blockIdx.x & 7) * (gridDim.x >> 3) + (blockIdx.x >> 3);
    const int m0 = (swz / nbn) * BM;
    const int n0 = (swz % nbn) * BN;

    const int wm  = wave >> 2;                // 0..1  (M half)
    const int wn  = wave & 3;                 // 0..3  (N quarter)
    const int r16 = lane & 15;
    const int kq  = lane >> 4;                // 0..3

    // ---- ds_read offsets (u16 within slot) ----
    // 8-way swizzle: u16 idx = (row*32 + kq*8) ^ (((row>>1)&3)<<3)
    //   (row&15 == r16 for both A and B frag rows, so use r16 bits 1-2)
    int aoff[8], boff[4];
#pragma unroll
    for (int f = 0; f < 8; ++f) {
        int row = wm * 128 + f * 16 + r16;
        aoff[f] = (row * 32 + kq * 8) ^ (((r16 >> 1) & 3) << 3);
    }
#pragma unroll
    for (int j = 0; j < 4; ++j) {
        int row = wn * 64 + j * 16 + r16;
        boff[j] = 8192 + ((row * 32 + kq * 8) ^ (((r16 >> 1) & 3) << 3));
    }

    // ---- staging: thread tau covers dest 16B granule tau of each 8KB half-panel ----
    // dest row = tau>>2, dest slot = tau&3; LDS[row][slot] must hold G[row][slot^((row>>1)&3)]
    // -> source slot = (t&3) ^ ((t>>3)&3)   (rule 21: same involution both sides)
    const int srow = t >> 2;                          // 0..127
    const int sswz = (t & 3) ^ ((t >> 3) & 3);        // swizzled source 16B slot
    const u16* pA = A + (size_t)(m0 + srow) * K_DIM + sswz * 8;
    const u16* pB = B + (size_t)(n0 + srow) * K_DIM + sswz * 8;
    const int dstW = wave * 512;                      // u16; hw adds lane*16B

    auto stageA = [&](int s, int tt) {
#pragma unroll
        for (int i = 0; i < 2; ++i)
            gload_lds16(pA + (size_t)i * 128 * K_DIM + tt * BK,
                        &lds[s * SLOT + i * 4096 + dstW]);
    };
    auto stageB = [&](int s, int tt) {
#pragma unroll
        for (int i = 0; i < 2; ++i)
            gload_lds16(pB + (size_t)i * 128 * K_DIM + tt * BK,
                        &lds[s * SLOT + 8192 + i * 4096 + dstW]);
    };

    f32x4 acc[8][4] = {};

    // ---- prologue: stage K0, K1; force K0 landed (vmcnt(4) leaves K1 in flight) ----
    stageA(0, 0); stageB(0, 0);
    stageA(1, 1); stageB(1, 1);
    asm volatile("s_waitcnt vmcnt(4)" ::: "memory");
    __builtin_amdgcn_s_barrier();

    for (int kt = 0; kt < NT; ++kt) {
        const int s  = kt & 3;
        const int sw = (kt + 2) & 3;
        const bool doStage = (kt + 2) < NT;

        bf16x8 bfr[4], afr[4];

        // ======== phase 0: B all + A frags 0..3 ========
#pragma unroll
        for (int j = 0; j < 4; ++j)
            bfr[j] = *(const bf16x8*)&lds[s * SLOT + boff[j]];
#pragma unroll
        for (int f = 0; f < 4; ++f)
            afr[f] = *(const bf16x8*)&lds[s * SLOT + aoff[f]];
        if (doStage) stageA(sw, kt + 2);
        __builtin_amdgcn_s_barrier();
        asm volatile("s_waitcnt lgkmcnt(0)" ::: "memory");
        __builtin_amdgcn_sched_barrier(0);
        __builtin_amdgcn_s_setprio(1);
#pragma unroll
        for (int f = 0; f < 4; ++f)
#pragma unroll
            for (int j = 0; j < 4; ++j)
                acc[f][j] = __builtin_amdgcn_mfma_f32_16x16x32_bf16(
                    afr[f], bfr[j], acc[f][j], 0, 0, 0);
        __builtin_amdgcn_s_setprio(0);
        __builtin_amdgcn_s_barrier();

        // ======== phase 1: A frags 4..7 (B kept in regs) ========
#pragma unroll
        for (int f = 0; f < 4; ++f)
            afr[f] = *(const bf16x8*)&lds[s * SLOT + aoff[4 + f]];
        if (doStage) stageB(sw, kt + 2);
        __builtin_amdgcn_s_barrier();
        asm volatile("s_waitcnt lgkmcnt(0)" ::: "memory");
        __builtin_amdgcn_sched_barrier(0);
        __builtin_amdgcn_s_setprio(1);
#pragma unroll
        for (int f = 0; f < 4; ++f)
#pragma unroll
            for (int j = 0; j < 4; ++j)
                acc[4 + f][j] = __builtin_amdgcn_mfma_f32_16x16x32_bf16(
                    afr[f], bfr[j], acc[4 + f][j], 0, 0, 0);
        __builtin_amdgcn_s_setprio(0);
        // gate next K-tile: everything except t+2's 4 loads must have landed
        if (doStage) asm volatile("s_waitcnt vmcnt(4)" ::: "memory");
        else         asm volatile("s_waitcnt vmcnt(0)" ::: "memory");
        __builtin_amdgcn_s_barrier();
    }

    // ---- epilogue: D mapping col = lane&15, row = (lane>>4)*4 + reg ----
#pragma unroll
    for (int f = 0; f < 8; ++f) {
        const int row = m0 + wm * 128 + f * 16 + kq * 4;
#pragma unroll
        for (int j = 0; j < 4; ++j) {
            const int col = n0 + wn * 64 + j * 16 + r16;
            float* cp = &C[(size_t)row * N_DIM + col];
#pragma unroll
            for (int r = 0; r < 4; ++r)
                cp[(size_t)r * N_DIM] = acc[f][j][r];
        }
    }
}

extern "C" void kernel_launch(void* const* d_in, const int* in_sizes, int n_in,
                              void* d_out, int out_size, void* d_ws, size_t ws_size,
                              hipStream_t stream) {
    const float* x  = (const float*)d_in[0];
    const int*   pw = (const int*)d_in[1];
    const float* sc = (const float*)d_in[2];
    const float* zp = (const float*)d_in[3];
    float* out = (float*)d_out;

    u16* Abf = (u16*)d_ws;                                   // 33,554,432 B
    u16* Wbf = (u16*)((char*)d_ws + (size_t)33554432);       // 90,177,536 B

    convert_x_kernel<<<8192, 256, 0, stream>>>(x, Abf);
    dequant_w_kernel<<<22016, 256, 0, stream>>>(pw, sc, zp, Wbf);

    const int grid = (M_DIM / BM) * (N_DIM / BN);            // 16 * 43 = 688
    gemm_bt_kernel<<<grid, 512, 0, stream>>>(Abf, Wbf, out);
}